// Round 8
// baseline (376.288 us; speedup 1.0000x reference)
//
#include <hip/hip_runtime.h>
#include <hip/hip_bf16.h>

#define NODES 50000
#define NEDGE 800000
#define CH 128          // all of IN/HID/OUT
#define NEG_SLOPE 0.2f
#define SCAN_CHUNK 2048
#define NBLK ((NODES + SCAN_CHUNK - 1) / SCAN_CHUNK)   // 25
#define NINF -1.0e30f
#define LOG2E 1.44269504088896340736f
#define NSLICE 400
#define SSLICE (NEDGE / NSLICE)       // 2000 edges per slice
#define ZB ((NODES + 255) / 256)      // 196 zero-blocks

typedef short short8 __attribute__((ext_vector_type(8)));
typedef float f32x4 __attribute__((ext_vector_type(4)));

__device__ __forceinline__ unsigned fbits(float f) {
    union { float f; unsigned u; } v; v.f = f; return v.u;
}
__device__ __forceinline__ float asf(unsigned u) {
    union { float f; unsigned u; } v; v.u = u; return v.f;
}
// fp32 -> bf16 (RNE)
__device__ __forceinline__ unsigned short f2bf(float f) {
    unsigned u = fbits(f);
    unsigned r = u + 0x7fff + ((u >> 16) & 1);
    return (unsigned short)(r >> 16);
}
__device__ __forceinline__ float bf2f(unsigned short h) {
    return asf(((unsigned)h) << 16);
}
__device__ __forceinline__ float lrelu(float x) {
    return fmaxf(x, NEG_SLOPE * x);
}
// 8 bf16 (as uint4) -> 8 fp32
__device__ __forceinline__ void bf8cvt(uint4 u, float* f) {
    f[0] = asf(u.x << 16); f[1] = asf(u.x & 0xFFFF0000u);
    f[2] = asf(u.y << 16); f[3] = asf(u.y & 0xFFFF0000u);
    f[4] = asf(u.z << 16); f[5] = asf(u.z & 0xFFFF0000u);
    f[6] = asf(u.w << 16); f[7] = asf(u.w & 0xFFFF0000u);
}
// dst-range set for XCD-partitioned CSR build
__device__ __forceinline__ int dset(int dst) {
    return (int)(((unsigned)dst * 8u) / 50000u);   // exact partition of [0,50000)
}

// ---------------------------------------------------------------------------
// prep: zero histogram + detect edge dtype + W->bf16 hi/lo transpose, fused.
// blocks [0,ZB): zero cnt (block 0 also detects int64 via ballot);
// blocks [ZB, ZB+256): wprep (64 blocks per W).
// ---------------------------------------------------------------------------
__global__ __launch_bounds__(256) void prep_kernel(const void* idx, int* flag,
                                                   int* cnt,
                                                   const float* __restrict__ W0,
                                                   const float* __restrict__ W1,
                                                   const float* __restrict__ W2,
                                                   const float* __restrict__ W3,
                                                   unsigned short* __restrict__ wbase) {
    int b = (int)blockIdx.x;
    if (b < ZB) {
        int t = b * 256 + (int)threadIdx.x;
        if (t < NODES) cnt[t] = 0;
        if (b == 0 && threadIdx.x < 64) {
            const int* w = (const int*)idx;
            int nz = (w[2 * threadIdx.x + 1] != 0) ? 1 : 0;
            unsigned long long bal = __ballot(nz);
            if (threadIdx.x == 0) *flag = (bal == 0ull) ? 1 : 0;
        }
        return;
    }
    int wb = b - ZB;                               // 0..255
    int which = wb >> 6;
    const float* W = (which == 0) ? W0 : (which == 1) ? W1 : (which == 2) ? W2 : W3;
    unsigned short* hiT = wbase + (size_t)which * 32768;
    unsigned short* loT = hiT + 16384;
    int i = (wb & 63) * 256 + (int)threadIdx.x;    // 0..16383
    int k = i >> 7, n = i & 127;
    float f = W[i];
    unsigned short h = f2bf(f);
    unsigned short l = f2bf(f - bf2f(h));
    hiT[n * CH + k] = h;
    loT[n * CH + k] = l;
}

// ---------------------------------------------------------------------------
// XCD-partitioned histogram
// ---------------------------------------------------------------------------
__global__ __launch_bounds__(256) void hist_part_kernel(const void* idx,
                                                        const int* flag,
                                                        int* cnt) {
    int set = blockIdx.x & 7;
    int slice = blockIdx.x >> 3;
    int base = slice * SSLICE;
    int endE = base + SSLICE;
    int i64 = *flag;
    const int* w = (const int*)idx;
    for (int e = base + (int)threadIdx.x; e < endE; e += 256) {
        int dst = i64 ? w[2 * (NEDGE + e)] : w[NEDGE + e];
        if (dset(dst) == set) atomicAdd(&cnt[dst], 1);
    }
}

__global__ __launch_bounds__(256) void scan1_kernel(const int* __restrict__ cnt,
                                                    int* __restrict__ bsum) {
    int base = blockIdx.x * SCAN_CHUNK + (int)threadIdx.x * 8;
    int s = 0;
    #pragma unroll
    for (int k = 0; k < 8; ++k) {
        int i = base + k;
        s += (i < NODES) ? cnt[i] : 0;
    }
    #pragma unroll
    for (int m = 1; m < 64; m <<= 1) s += __shfl_xor(s, m);
    __shared__ int ws[4];
    if ((threadIdx.x & 63) == 0) ws[threadIdx.x >> 6] = s;
    __syncthreads();
    if (threadIdx.x == 0) bsum[blockIdx.x] = ws[0] + ws[1] + ws[2] + ws[3];
}

__global__ __launch_bounds__(256) void scan3_kernel(const int* __restrict__ cnt,
                                                    const int* __restrict__ bsum,
                                                    int* __restrict__ offs,
                                                    int* __restrict__ cursor) {
    int tid = (int)threadIdx.x;
    int bpre = 0;
    #pragma unroll
    for (int b = 0; b < NBLK; ++b) bpre += (b < (int)blockIdx.x) ? bsum[b] : 0;

    int base = blockIdx.x * SCAN_CHUNK + tid * 8;
    int v[8];
    int s = 0;
    #pragma unroll
    for (int k = 0; k < 8; ++k) {
        int i = base + k;
        v[k] = (i < NODES) ? cnt[i] : 0;
        s += v[k];
    }
    int lane = tid & 63;
    int incl = s;
    #pragma unroll
    for (int m = 1; m < 64; m <<= 1) {
        int t = __shfl_up(incl, m);
        if (lane >= m) incl += t;
    }
    __shared__ int wtot[4];
    if (lane == 63) wtot[tid >> 6] = incl;
    __syncthreads();
    int w = tid >> 6;
    int wbase = 0;
    #pragma unroll
    for (int k = 0; k < 4; ++k) wbase += (k < w) ? wtot[k] : 0;
    int excl = bpre + wbase + (incl - s);
    #pragma unroll
    for (int k = 0; k < 8; ++k) {
        int i = base + k;
        if (i < NODES) { offs[i] = excl; cursor[i] = excl; }
        excl += v[k];
    }
    if (blockIdx.x == 0 && tid == 0) offs[NODES] = NEDGE;
}

// ---------------------------------------------------------------------------
// XCD-partitioned scatter
// ---------------------------------------------------------------------------
__global__ __launch_bounds__(256) void scatter_part_kernel(const void* idx,
                                                           const int* flag,
                                                           int* cursor,
                                                           int* __restrict__ srcs) {
    int set = blockIdx.x & 7;
    int slice = blockIdx.x >> 3;
    int base = slice * SSLICE;
    int endE = base + SSLICE;
    int i64 = *flag;
    const int* w = (const int*)idx;
    for (int e = base + (int)threadIdx.x; e < endE; e += 256) {
        int dst = i64 ? w[2 * (NEDGE + e)] : w[NEDGE + e];
        if (dset(dst) == set) {
            int src = i64 ? w[2 * e] : w[e];
            int pos = atomicAdd(&cursor[dst], 1);
            srcs[pos] = src;
        }
    }
}

// ---------------------------------------------------------------------------
// Layer-1 GEMM (fp32 input, LDS-staged split-bf16 MFMA):
// Ylb = bf16(X@Wl + bl), Yr = X@Wr + br (fp32).
// ---------------------------------------------------------------------------
#define GR 64
#define LDP 136   // padded row stride in shorts (272 B)

__global__ __launch_bounds__(256) void gemm_dual_mfma(
        const float* __restrict__ X,
        const unsigned short* __restrict__ whTl, const unsigned short* __restrict__ wlTl,
        const unsigned short* __restrict__ whTr, const unsigned short* __restrict__ wlTr,
        const float* __restrict__ bl, const float* __restrict__ br,
        unsigned short* __restrict__ Ylb, float* __restrict__ Yr, int nrows) {
    __shared__ unsigned short xh[GR][LDP];
    __shared__ unsigned short xlo[GR][LDP];

    int r0 = blockIdx.x * GR;
    int tid = (int)threadIdx.x;

    // ---- stage X tile: fp32 -> hi/lo bf16 (truncation split), packed ----
    {
        int row = tid >> 2;              // 0..63
        int c0 = (tid & 3) * 32;         // col start
        const float* src = X + (size_t)(r0 + row) * CH + c0;
        bool valid = (r0 + row) < nrows;
        #pragma unroll
        for (int j = 0; j < 32; j += 4) {
            float4 v = valid ? *(const float4*)(src + j)
                             : make_float4(0.f, 0.f, 0.f, 0.f);
            unsigned ux = fbits(v.x), uy = fbits(v.y);
            unsigned uz = fbits(v.z), uw = fbits(v.w);
            unsigned hx = ux & 0xFFFF0000u, hy = uy & 0xFFFF0000u;
            unsigned hz = uz & 0xFFFF0000u, hw = uw & 0xFFFF0000u;
            uint2 hp;
            hp.x = (ux >> 16) | hy;
            hp.y = (uz >> 16) | hw;
            float lx = v.x - asf(hx), ly = v.y - asf(hy);
            float lz = v.z - asf(hz), lw = v.w - asf(hw);
            uint2 lp;
            lp.x = (fbits(lx) >> 16) | (fbits(ly) & 0xFFFF0000u);
            lp.y = (fbits(lz) >> 16) | (fbits(lw) & 0xFFFF0000u);
            *(uint2*)&xh[row][c0 + j]  = hp;
            *(uint2*)&xlo[row][c0 + j] = lp;
        }
    }
    __syncthreads();

    int wave = tid >> 6;      // 0..3: n-quarter
    int lane = tid & 63;
    int l15 = lane & 15, q = lane >> 4;

    f32x4 acc[4][4];
    #pragma unroll
    for (int mt = 0; mt < 4; ++mt)
        #pragma unroll
        for (int nt = 0; nt < 4; ++nt) acc[mt][nt] = (f32x4)0.f;

    const unsigned short* bhp[4];
    const unsigned short* blp_[4];
    int ncol[4];
    #pragma unroll
    for (int nt = 0; nt < 4; ++nt) {
        int n = (wave * 4 + nt) * 16 + l15;       // 0..255
        ncol[nt] = n;
        int nn = n & 127;
        bhp[nt]  = ((n < CH) ? whTl : whTr) + (size_t)nn * CH;
        blp_[nt] = ((n < CH) ? wlTl : wlTr) + (size_t)nn * CH;
    }

    for (int kt = 0; kt < 4; ++kt) {
        int kofs = kt * 32 + q * 8;
        short8 ah[4], al[4];
        #pragma unroll
        for (int mt = 0; mt < 4; ++mt) {
            ah[mt] = *(const short8*)&xh[mt * 16 + l15][kofs];
            al[mt] = *(const short8*)&xlo[mt * 16 + l15][kofs];
        }
        #pragma unroll
        for (int nt = 0; nt < 4; ++nt) {
            short8 bh8 = *(const short8*)(bhp[nt] + kofs);
            short8 bl8 = *(const short8*)(blp_[nt] + kofs);
            #pragma unroll
            for (int mt = 0; mt < 4; ++mt) {
                acc[mt][nt] = __builtin_amdgcn_mfma_f32_16x16x32_bf16(
                                  ah[mt], bh8, acc[mt][nt], 0, 0, 0);
                acc[mt][nt] = __builtin_amdgcn_mfma_f32_16x16x32_bf16(
                                  al[mt], bh8, acc[mt][nt], 0, 0, 0);
                acc[mt][nt] = __builtin_amdgcn_mfma_f32_16x16x32_bf16(
                                  ah[mt], bl8, acc[mt][nt], 0, 0, 0);
            }
        }
    }

    // ---- epilogue: C/D layout col=lane&15, row=q*4+reg ----
    #pragma unroll
    for (int nt = 0; nt < 4; ++nt) {
        int n = ncol[nt];
        int nc = n & 127;
        if (n < CH) {
            float bv = bl[nc];
            #pragma unroll
            for (int mt = 0; mt < 4; ++mt)
                #pragma unroll
                for (int reg = 0; reg < 4; ++reg) {
                    int row = r0 + mt * 16 + q * 4 + reg;
                    if (row < nrows)
                        Ylb[(size_t)row * CH + nc] = f2bf(acc[mt][nt][reg] + bv);
                }
        } else {
            float bv = br[nc];
            #pragma unroll
            for (int mt = 0; mt < 4; ++mt)
                #pragma unroll
                for (int reg = 0; reg < 4; ++reg) {
                    int row = r0 + mt * 16 + q * 4 + reg;
                    if (row < nrows)
                        Yr[(size_t)row * CH + nc] = acc[mt][nt][reg] + bv;
                }
        }
    }
}

// ---------------------------------------------------------------------------
// Layer-2 GEMM (input pre-split as bf16 hi/lo planes): NO LDS, no barrier.
// A-fragments load straight from global (L1-resident 64-row tile).
// ---------------------------------------------------------------------------
__global__ __launch_bounds__(256) void gemm_dual_mfma_pl(
        const unsigned short* __restrict__ Ah, const unsigned short* __restrict__ Al,
        const unsigned short* __restrict__ whTl, const unsigned short* __restrict__ wlTl,
        const unsigned short* __restrict__ whTr, const unsigned short* __restrict__ wlTr,
        const float* __restrict__ bl, const float* __restrict__ br,
        unsigned short* __restrict__ Ylb, float* __restrict__ Yr, int nrows) {
    int r0 = blockIdx.x * GR;
    int tid = (int)threadIdx.x;
    int wave = tid >> 6;
    int lane = tid & 63;
    int l15 = lane & 15, q = lane >> 4;

    // per-lane A row offsets (clamped; OOB rows discarded at store)
    size_t offA[4];
    #pragma unroll
    for (int mt = 0; mt < 4; ++mt) {
        int row = r0 + mt * 16 + l15;
        if (row > nrows - 1) row = nrows - 1;
        offA[mt] = (size_t)row * CH;
    }

    f32x4 acc[4][4];
    #pragma unroll
    for (int mt = 0; mt < 4; ++mt)
        #pragma unroll
        for (int nt = 0; nt < 4; ++nt) acc[mt][nt] = (f32x4)0.f;

    const unsigned short* bhp[4];
    const unsigned short* blp_[4];
    int ncol[4];
    #pragma unroll
    for (int nt = 0; nt < 4; ++nt) {
        int n = (wave * 4 + nt) * 16 + l15;
        ncol[nt] = n;
        int nn = n & 127;
        bhp[nt]  = ((n < CH) ? whTl : whTr) + (size_t)nn * CH;
        blp_[nt] = ((n < CH) ? wlTl : wlTr) + (size_t)nn * CH;
    }

    for (int kt = 0; kt < 4; ++kt) {
        int kofs = kt * 32 + q * 8;
        short8 ah[4], al[4];
        #pragma unroll
        for (int mt = 0; mt < 4; ++mt) {
            ah[mt] = *(const short8*)(Ah + offA[mt] + kofs);
            al[mt] = *(const short8*)(Al + offA[mt] + kofs);
        }
        #pragma unroll
        for (int nt = 0; nt < 4; ++nt) {
            short8 bh8 = *(const short8*)(bhp[nt] + kofs);
            short8 bl8 = *(const short8*)(blp_[nt] + kofs);
            #pragma unroll
            for (int mt = 0; mt < 4; ++mt) {
                acc[mt][nt] = __builtin_amdgcn_mfma_f32_16x16x32_bf16(
                                  ah[mt], bh8, acc[mt][nt], 0, 0, 0);
                acc[mt][nt] = __builtin_amdgcn_mfma_f32_16x16x32_bf16(
                                  al[mt], bh8, acc[mt][nt], 0, 0, 0);
                acc[mt][nt] = __builtin_amdgcn_mfma_f32_16x16x32_bf16(
                                  ah[mt], bl8, acc[mt][nt], 0, 0, 0);
            }
        }
    }

    #pragma unroll
    for (int nt = 0; nt < 4; ++nt) {
        int n = ncol[nt];
        int nc = n & 127;
        if (n < CH) {
            float bv = bl[nc];
            #pragma unroll
            for (int mt = 0; mt < 4; ++mt)
                #pragma unroll
                for (int reg = 0; reg < 4; ++reg) {
                    int row = r0 + mt * 16 + q * 4 + reg;
                    if (row < nrows)
                        Ylb[(size_t)row * CH + nc] = f2bf(acc[mt][nt][reg] + bv);
                }
        } else {
            float bv = br[nc];
            #pragma unroll
            for (int mt = 0; mt < 4; ++mt)
                #pragma unroll
                for (int reg = 0; reg < 4; ++reg) {
                    int row = r0 + mt * 16 + q * 4 + reg;
                    if (row < nrows)
                        Yr[(size_t)row * CH + nc] = acc[mt][nt][reg] + bv;
                }
        }
    }
}

// ---------------------------------------------------------------------------
// Fused GATv2 edge pass, v5: one node per wave; 16 lanes per edge row
// (8 bf16 ch/lane via uint4); four quarter-wave online-softmax states, each
// quarter processing TWO edges per iteration (8 edges in flight) with one
// shared rescale; prefetch of the next pair. Merge via shfl_xor 16/32.
// SPLITOUT: write output as trunc-split bf16 hi/lo planes (layer-1 -> gemm2).
// ---------------------------------------------------------------------------
template <int HEADS, bool RELU, bool SPLITOUT>
__global__ __launch_bounds__(256) void node_pass(
        const unsigned short* __restrict__ xlb,   // [N][128] bf16 bits
        const float* __restrict__ xr,
        const float* __restrict__ att,    // 128 floats, flat (H, C/H)
        const float* __restrict__ bias,   // 128 floats
        const int* __restrict__ offs, const int* __restrict__ srcs,
        float* __restrict__ outf,
        unsigned short* __restrict__ outh, unsigned short* __restrict__ outl) {
    constexpr int GL = (CH / HEADS) / 8;     // lanes per head group: 4 or 16
    int wave = (int)threadIdx.x >> 6;
    int i = blockIdx.x * 4 + wave;
    int lane = (int)threadIdx.x & 63;
    int g = lane >> 4;                       // quarter 0..3
    int l16 = lane & 15;
    int c0 = l16 * 8;                        // this lane's 8 channels

    float r[8], a[8], s[8];
    {
        const float4* xrp = (const float4*)(xr + (size_t)i * CH + c0);
        float4 r0 = xrp[0], r1 = xrp[1];
        r[0]=r0.x; r[1]=r0.y; r[2]=r0.z; r[3]=r0.w;
        r[4]=r1.x; r[5]=r1.y; r[6]=r1.z; r[7]=r1.w;
        const float4* atp = (const float4*)(att + c0);
        float4 a0 = atp[0], a1 = atp[1];
        a[0]=a0.x*LOG2E; a[1]=a0.y*LOG2E; a[2]=a0.z*LOG2E; a[3]=a0.w*LOG2E;
        a[4]=a1.x*LOG2E; a[5]=a1.y*LOG2E; a[6]=a1.z*LOG2E; a[7]=a1.w*LOG2E;
    }
    // self row (bf16)
    uint4 us = *(const uint4*)(xlb + (size_t)i * CH + c0);
    bf8cvt(us, s);

    float ts = 0.f;
    #pragma unroll
    for (int c = 0; c < 8; ++c) ts += lrelu(s[c] + r[c]) * a[c];
    #pragma unroll
    for (int msk = 1; msk < GL; msk <<= 1) ts += __shfl_xor(ts, msk);

    float m = (g == 0) ? ts : NINF;
    float d = (g == 0) ? 1.f : 0.f;
    float acc[8];
    #pragma unroll
    for (int c = 0; c < 8; ++c) acc[c] = (g == 0) ? s[c] : 0.f;

    int beg = offs[i], end = offs[i + 1];
    int deg = end - beg;
    int iters = (deg + 7) >> 3;
    if (iters > 0) {
        int last = end - 1;
        int e = beg + g;                      // quarter g owns e and e+4 (+8k)
        int s0i = srcs[min(e, last)];
        int s1i = srcs[min(e + 4, last)];
        uint4 u0 = *(const uint4*)(xlb + (size_t)s0i * CH + c0);
        uint4 u1 = *(const uint4*)(xlb + (size_t)s1i * CH + c0);

        for (int it = 0; it < iters; ++it, e += 8) {
            bool v0 = e < end, v1 = (e + 4) < end;
            // prefetch next pair (clamped: stays in this node's segment)
            int sn0 = srcs[min(e + 8, last)];
            int sn1 = srcs[min(e + 12, last)];
            uint4 un0 = *(const uint4*)(xlb + (size_t)sn0 * CH + c0);
            uint4 un1 = *(const uint4*)(xlb + (size_t)sn1 * CH + c0);

            float f0[8], f1[8];
            bf8cvt(u0, f0);
            bf8cvt(u1, f1);
            float t0 = 0.f, t1 = 0.f;
            #pragma unroll
            for (int c = 0; c < 8; ++c) {
                t0 += lrelu(f0[c] + r[c]) * a[c];
                t1 += lrelu(f1[c] + r[c]) * a[c];
            }
            #pragma unroll
            for (int msk = 1; msk < GL; msk <<= 1) {
                t0 += __shfl_xor(t0, msk);
                t1 += __shfl_xor(t1, msk);
            }
            t0 = v0 ? t0 : NINF;
            t1 = v1 ? t1 : NINF;

            float nm = fmaxf(m, fmaxf(t0, t1));
            float sc = exp2f(m - nm);
            float p0 = v0 ? exp2f(t0 - nm) : 0.f;
            float p1 = v1 ? exp2f(t1 - nm) : 0.f;
            d = d * sc + p0 + p1;
            #pragma unroll
            for (int c = 0; c < 8; ++c)
                acc[c] = acc[c] * sc + p0 * f0[c] + p1 * f1[c];
            m = nm;
            u0 = un0; u1 = un1;
        }
    }

    // merge the 4 quarter-wave states (butterfly: all lanes converge)
    #pragma unroll
    for (int msk = 16; msk <= 32; msk <<= 1) {
        float mo  = __shfl_xor(m, msk);
        float dof = __shfl_xor(d, msk);
        float nm = fmaxf(m, mo);
        float s0 = exp2f(m - nm), s1 = exp2f(mo - nm);
        d = d * s0 + dof * s1;
        #pragma unroll
        for (int c = 0; c < 8; ++c) {
            float ao = __shfl_xor(acc[c], msk);
            acc[c] = acc[c] * s0 + ao * s1;
        }
        m = nm;
    }

    if (g == 0) {
        float inv = 1.0f / d;
        const float4* bp = (const float4*)(bias + c0);
        float4 b0 = bp[0], b1 = bp[1];
        float bb[8] = {b0.x, b0.y, b0.z, b0.w, b1.x, b1.y, b1.z, b1.w};
        float o[8];
        #pragma unroll
        for (int c = 0; c < 8; ++c) {
            o[c] = acc[c] * inv + bb[c];
            if (RELU) o[c] = fmaxf(o[c], 0.f);
        }
        if (SPLITOUT) {
            unsigned hu[8];
            float lo[8];
            #pragma unroll
            for (int c = 0; c < 8; ++c) {
                hu[c] = fbits(o[c]) & 0xFFFF0000u;
                lo[c] = o[c] - asf(hu[c]);
            }
            uint4 ph, pl;
            ph.x = (hu[0] >> 16) | hu[1];  ph.y = (hu[2] >> 16) | hu[3];
            ph.z = (hu[4] >> 16) | hu[5];  ph.w = (hu[6] >> 16) | hu[7];
            pl.x = (fbits(lo[0]) >> 16) | (fbits(lo[1]) & 0xFFFF0000u);
            pl.y = (fbits(lo[2]) >> 16) | (fbits(lo[3]) & 0xFFFF0000u);
            pl.z = (fbits(lo[4]) >> 16) | (fbits(lo[5]) & 0xFFFF0000u);
            pl.w = (fbits(lo[6]) >> 16) | (fbits(lo[7]) & 0xFFFF0000u);
            *(uint4*)(outh + (size_t)i * CH + c0) = ph;
            *(uint4*)(outl + (size_t)i * CH + c0) = pl;
        } else {
            float4 w0 = make_float4(o[0], o[1], o[2], o[3]);
            float4 w1 = make_float4(o[4], o[5], o[6], o[7]);
            float4* op = (float4*)(outf + (size_t)i * CH + c0);
            op[0] = w0; op[1] = w1;
        }
    }
}

// ---------------------------------------------------------------------------
extern "C" void kernel_launch(void* const* d_in, const int* in_sizes, int n_in,
                              void* d_out, int out_size, void* d_ws, size_t ws_size,
                              hipStream_t stream) {
    const float* x     = (const float*)d_in[0];
    const void*  eidx  = d_in[1];
    const float* W1l   = (const float*)d_in[2];
    const float* b1l   = (const float*)d_in[3];
    const float* W1r   = (const float*)d_in[4];
    const float* b1r   = (const float*)d_in[5];
    const float* att1  = (const float*)d_in[6];
    const float* bias1 = (const float*)d_in[7];
    const float* W2l   = (const float*)d_in[8];
    const float* b2l   = (const float*)d_in[9];
    const float* W2r   = (const float*)d_in[10];
    const float* b2r   = (const float*)d_in[11];
    const float* att2  = (const float*)d_in[12];
    const float* bias2 = (const float*)d_in[13];
    float* out = (float*)d_out;

    // workspace layout
    unsigned short* xlb = (unsigned short*)d_ws;        // N*128 bf16 (attn side)
    float* xr = (float*)(xlb + (size_t)NODES * CH);     // N*128 fp32 (dst side)
    unsigned short* hbh = (unsigned short*)(xr + (size_t)NODES * CH); // N*128 u16
    unsigned short* hbl = hbh + (size_t)NODES * CH;     // N*128 u16
    int* offs   = (int*)(hbl + (size_t)NODES * CH);     // N+1
    int* cnt    = offs + (NODES + 1);                   // N
    int* cursor = cnt + NODES;                          // N
    int* srcs   = cursor + NODES;                       // E
    int* flag   = srcs + NEDGE;                         // 1
    int* bsum   = flag + 1;                             // NBLK
    unsigned short* wbuf =
        (unsigned short*)(((uintptr_t)(bsum + NBLK) + 15) & ~(uintptr_t)15);
    unsigned short* w1lh = wbuf;              unsigned short* w1ll = wbuf + 16384;
    unsigned short* w1rh = wbuf + 32768;      unsigned short* w1rl = wbuf + 49152;
    unsigned short* w2lh = wbuf + 65536;      unsigned short* w2ll = wbuf + 81920;
    unsigned short* w2rh = wbuf + 98304;      unsigned short* w2rl = wbuf + 114688;

    const int GG = (NODES + GR - 1) / GR;
    const int PG = NSLICE * 8;               // partitioned hist/scatter grid

    // prep (zero cnt + dtype detect + W split/transpose) and CSR build
    prep_kernel<<<ZB + 256, 256, 0, stream>>>(eidx, flag, cnt,
                                              W1l, W1r, W2l, W2r, wbuf);
    hist_part_kernel<<<PG, 256, 0, stream>>>(eidx, flag, cnt);
    scan1_kernel<<<NBLK, 256, 0, stream>>>(cnt, bsum);
    scan3_kernel<<<NBLK, 256, 0, stream>>>(cnt, bsum, offs, cursor);
    scatter_part_kernel<<<PG, 256, 0, stream>>>(eidx, flag, cursor, srcs);

    // layer 1
    gemm_dual_mfma<<<GG, 256, 0, stream>>>(x, w1lh, w1ll, w1rh, w1rl,
                                           b1l, b1r, xlb, xr, NODES);
    node_pass<4, true, true><<<(NODES + 3) / 4, 256, 0, stream>>>(
        xlb, xr, att1, bias1, offs, srcs, nullptr, hbh, hbl);

    // layer 2
    gemm_dual_mfma_pl<<<GG, 256, 0, stream>>>(hbh, hbl, w2lh, w2ll, w2rh, w2rl,
                                              b2l, b2r, xlb, xr, NODES);
    node_pass<1, false, false><<<(NODES + 3) / 4, 256, 0, stream>>>(
        xlb, xr, att2, bias2, offs, srcs, out, nullptr, nullptr);
}

// Round 9
// 364.246 us; speedup vs baseline: 1.0331x; 1.0331x over previous
//
#include <hip/hip_runtime.h>
#include <hip/hip_bf16.h>

#define NODES 50000
#define NEDGE 800000
#define CH 128          // all of IN/HID/OUT
#define NEG_SLOPE 0.2f
#define SCAN_CHUNK 2048
#define NBLK ((NODES + SCAN_CHUNK - 1) / SCAN_CHUNK)   // 25
#define NINF -1.0e30f
#define LOG2E 1.44269504088896340736f
#define NSLICE 400
#define SSLICE (NEDGE / NSLICE)       // 2000 edges per slice
#define ZB ((NODES + 255) / 256)      // 196 zero-blocks

typedef short short8 __attribute__((ext_vector_type(8)));
typedef float f32x4 __attribute__((ext_vector_type(4)));
typedef float f32x2 __attribute__((ext_vector_type(2)));

__device__ __forceinline__ unsigned fbits(float f) {
    union { float f; unsigned u; } v; v.f = f; return v.u;
}
__device__ __forceinline__ float asf(unsigned u) {
    union { float f; unsigned u; } v; v.u = u; return v.f;
}
// fp32 -> bf16 (RNE)
__device__ __forceinline__ unsigned short f2bf(float f) {
    unsigned u = fbits(f);
    unsigned r = u + 0x7fff + ((u >> 16) & 1);
    return (unsigned short)(r >> 16);
}
__device__ __forceinline__ float bf2f(unsigned short h) {
    return asf(((unsigned)h) << 16);
}
// 8 bf16 (as uint4) -> 4 x float2 (packed-math friendly)
__device__ __forceinline__ void bf8cvt2(uint4 u, f32x2* f) {
    f[0] = (f32x2){asf(u.x << 16), asf(u.x & 0xFFFF0000u)};
    f[1] = (f32x2){asf(u.y << 16), asf(u.y & 0xFFFF0000u)};
    f[2] = (f32x2){asf(u.z << 16), asf(u.z & 0xFFFF0000u)};
    f[3] = (f32x2){asf(u.w << 16), asf(u.w & 0xFFFF0000u)};
}
// dst-range set for XCD-partitioned CSR build
__device__ __forceinline__ int dset(int dst) {
    return (int)(((unsigned)dst * 8u) / 50000u);   // exact partition of [0,50000)
}

// ---------------------------------------------------------------------------
// prep: zero histogram + detect edge dtype + W->bf16 hi/lo transpose, fused.
// ---------------------------------------------------------------------------
__global__ __launch_bounds__(256) void prep_kernel(const void* idx, int* flag,
                                                   int* cnt,
                                                   const float* __restrict__ W0,
                                                   const float* __restrict__ W1,
                                                   const float* __restrict__ W2,
                                                   const float* __restrict__ W3,
                                                   unsigned short* __restrict__ wbase) {
    int b = (int)blockIdx.x;
    if (b < ZB) {
        int t = b * 256 + (int)threadIdx.x;
        if (t < NODES) cnt[t] = 0;
        if (b == 0 && threadIdx.x < 64) {
            const int* w = (const int*)idx;
            int nz = (w[2 * threadIdx.x + 1] != 0) ? 1 : 0;
            unsigned long long bal = __ballot(nz);
            if (threadIdx.x == 0) *flag = (bal == 0ull) ? 1 : 0;
        }
        return;
    }
    int wb = b - ZB;                               // 0..255
    int which = wb >> 6;
    const float* W = (which == 0) ? W0 : (which == 1) ? W1 : (which == 2) ? W2 : W3;
    unsigned short* hiT = wbase + (size_t)which * 32768;
    unsigned short* loT = hiT + 16384;
    int i = (wb & 63) * 256 + (int)threadIdx.x;    // 0..16383
    int k = i >> 7, n = i & 127;
    float f = W[i];
    unsigned short h = f2bf(f);
    unsigned short l = f2bf(f - bf2f(h));
    hiT[n * CH + k] = h;
    loT[n * CH + k] = l;
}

// ---------------------------------------------------------------------------
// XCD-partitioned histogram
// ---------------------------------------------------------------------------
__global__ __launch_bounds__(256) void hist_part_kernel(const void* idx,
                                                        const int* flag,
                                                        int* cnt) {
    int set = blockIdx.x & 7;
    int slice = blockIdx.x >> 3;
    int base = slice * SSLICE;
    int endE = base + SSLICE;
    int i64 = *flag;
    const int* w = (const int*)idx;
    for (int e = base + (int)threadIdx.x; e < endE; e += 256) {
        int dst = i64 ? w[2 * (NEDGE + e)] : w[NEDGE + e];
        if (dset(dst) == set) atomicAdd(&cnt[dst], 1);
    }
}

__global__ __launch_bounds__(256) void scan1_kernel(const int* __restrict__ cnt,
                                                    int* __restrict__ bsum) {
    int base = blockIdx.x * SCAN_CHUNK + (int)threadIdx.x * 8;
    int s = 0;
    #pragma unroll
    for (int k = 0; k < 8; ++k) {
        int i = base + k;
        s += (i < NODES) ? cnt[i] : 0;
    }
    #pragma unroll
    for (int m = 1; m < 64; m <<= 1) s += __shfl_xor(s, m);
    __shared__ int ws[4];
    if ((threadIdx.x & 63) == 0) ws[threadIdx.x >> 6] = s;
    __syncthreads();
    if (threadIdx.x == 0) bsum[blockIdx.x] = ws[0] + ws[1] + ws[2] + ws[3];
}

__global__ __launch_bounds__(256) void scan3_kernel(const int* __restrict__ cnt,
                                                    const int* __restrict__ bsum,
                                                    int* __restrict__ offs,
                                                    int* __restrict__ cursor) {
    int tid = (int)threadIdx.x;
    int bpre = 0;
    #pragma unroll
    for (int b = 0; b < NBLK; ++b) bpre += (b < (int)blockIdx.x) ? bsum[b] : 0;

    int base = blockIdx.x * SCAN_CHUNK + tid * 8;
    int v[8];
    int s = 0;
    #pragma unroll
    for (int k = 0; k < 8; ++k) {
        int i = base + k;
        v[k] = (i < NODES) ? cnt[i] : 0;
        s += v[k];
    }
    int lane = tid & 63;
    int incl = s;
    #pragma unroll
    for (int m = 1; m < 64; m <<= 1) {
        int t = __shfl_up(incl, m);
        if (lane >= m) incl += t;
    }
    __shared__ int wtot[4];
    if (lane == 63) wtot[tid >> 6] = incl;
    __syncthreads();
    int w = tid >> 6;
    int wbase = 0;
    #pragma unroll
    for (int k = 0; k < 4; ++k) wbase += (k < w) ? wtot[k] : 0;
    int excl = bpre + wbase + (incl - s);
    #pragma unroll
    for (int k = 0; k < 8; ++k) {
        int i = base + k;
        if (i < NODES) { offs[i] = excl; cursor[i] = excl; }
        excl += v[k];
    }
    if (blockIdx.x == 0 && tid == 0) offs[NODES] = NEDGE;
}

// ---------------------------------------------------------------------------
// XCD-partitioned scatter
// ---------------------------------------------------------------------------
__global__ __launch_bounds__(256) void scatter_part_kernel(const void* idx,
                                                           const int* flag,
                                                           int* cursor,
                                                           int* __restrict__ srcs) {
    int set = blockIdx.x & 7;
    int slice = blockIdx.x >> 3;
    int base = slice * SSLICE;
    int endE = base + SSLICE;
    int i64 = *flag;
    const int* w = (const int*)idx;
    for (int e = base + (int)threadIdx.x; e < endE; e += 256) {
        int dst = i64 ? w[2 * (NEDGE + e)] : w[NEDGE + e];
        if (dset(dst) == set) {
            int src = i64 ? w[2 * e] : w[e];
            int pos = atomicAdd(&cursor[dst], 1);
            srcs[pos] = src;
        }
    }
}

// ---------------------------------------------------------------------------
// Layer-1 GEMM (fp32 input, LDS-staged split-bf16 MFMA):
// Ylb = bf16(X@Wl + bl), Yr = X@Wr + br (fp32).
// ---------------------------------------------------------------------------
#define GR 64
#define LDP 136   // padded row stride in shorts (272 B)

__global__ __launch_bounds__(256) void gemm_dual_mfma(
        const float* __restrict__ X,
        const unsigned short* __restrict__ whTl, const unsigned short* __restrict__ wlTl,
        const unsigned short* __restrict__ whTr, const unsigned short* __restrict__ wlTr,
        const float* __restrict__ bl, const float* __restrict__ br,
        unsigned short* __restrict__ Ylb, float* __restrict__ Yr, int nrows) {
    __shared__ unsigned short xh[GR][LDP];
    __shared__ unsigned short xlo[GR][LDP];

    int r0 = blockIdx.x * GR;
    int tid = (int)threadIdx.x;

    // ---- stage X tile: fp32 -> hi/lo bf16 (truncation split), packed ----
    {
        int row = tid >> 2;              // 0..63
        int c0 = (tid & 3) * 32;         // col start
        const float* src = X + (size_t)(r0 + row) * CH + c0;
        bool valid = (r0 + row) < nrows;
        #pragma unroll
        for (int j = 0; j < 32; j += 4) {
            float4 v = valid ? *(const float4*)(src + j)
                             : make_float4(0.f, 0.f, 0.f, 0.f);
            unsigned ux = fbits(v.x), uy = fbits(v.y);
            unsigned uz = fbits(v.z), uw = fbits(v.w);
            unsigned hx = ux & 0xFFFF0000u, hy = uy & 0xFFFF0000u;
            unsigned hz = uz & 0xFFFF0000u, hw = uw & 0xFFFF0000u;
            uint2 hp;
            hp.x = (ux >> 16) | hy;
            hp.y = (uz >> 16) | hw;
            float lx = v.x - asf(hx), ly = v.y - asf(hy);
            float lz = v.z - asf(hz), lw = v.w - asf(hw);
            uint2 lp;
            lp.x = (fbits(lx) >> 16) | (fbits(ly) & 0xFFFF0000u);
            lp.y = (fbits(lz) >> 16) | (fbits(lw) & 0xFFFF0000u);
            *(uint2*)&xh[row][c0 + j]  = hp;
            *(uint2*)&xlo[row][c0 + j] = lp;
        }
    }
    __syncthreads();

    int wave = tid >> 6;      // 0..3: n-quarter
    int lane = tid & 63;
    int l15 = lane & 15, q = lane >> 4;

    f32x4 acc[4][4];
    #pragma unroll
    for (int mt = 0; mt < 4; ++mt)
        #pragma unroll
        for (int nt = 0; nt < 4; ++nt) acc[mt][nt] = (f32x4)0.f;

    const unsigned short* bhp[4];
    const unsigned short* blp_[4];
    int ncol[4];
    #pragma unroll
    for (int nt = 0; nt < 4; ++nt) {
        int n = (wave * 4 + nt) * 16 + l15;       // 0..255
        ncol[nt] = n;
        int nn = n & 127;
        bhp[nt]  = ((n < CH) ? whTl : whTr) + (size_t)nn * CH;
        blp_[nt] = ((n < CH) ? wlTl : wlTr) + (size_t)nn * CH;
    }

    for (int kt = 0; kt < 4; ++kt) {
        int kofs = kt * 32 + q * 8;
        short8 ah[4], al[4];
        #pragma unroll
        for (int mt = 0; mt < 4; ++mt) {
            ah[mt] = *(const short8*)&xh[mt * 16 + l15][kofs];
            al[mt] = *(const short8*)&xlo[mt * 16 + l15][kofs];
        }
        #pragma unroll
        for (int nt = 0; nt < 4; ++nt) {
            short8 bh8 = *(const short8*)(bhp[nt] + kofs);
            short8 bl8 = *(const short8*)(blp_[nt] + kofs);
            #pragma unroll
            for (int mt = 0; mt < 4; ++mt) {
                acc[mt][nt] = __builtin_amdgcn_mfma_f32_16x16x32_bf16(
                                  ah[mt], bh8, acc[mt][nt], 0, 0, 0);
                acc[mt][nt] = __builtin_amdgcn_mfma_f32_16x16x32_bf16(
                                  al[mt], bh8, acc[mt][nt], 0, 0, 0);
                acc[mt][nt] = __builtin_amdgcn_mfma_f32_16x16x32_bf16(
                                  ah[mt], bl8, acc[mt][nt], 0, 0, 0);
            }
        }
    }

    // ---- epilogue: C/D layout col=lane&15, row=q*4+reg ----
    #pragma unroll
    for (int nt = 0; nt < 4; ++nt) {
        int n = ncol[nt];
        int nc = n & 127;
        if (n < CH) {
            float bv = bl[nc];
            #pragma unroll
            for (int mt = 0; mt < 4; ++mt)
                #pragma unroll
                for (int reg = 0; reg < 4; ++reg) {
                    int row = r0 + mt * 16 + q * 4 + reg;
                    if (row < nrows)
                        Ylb[(size_t)row * CH + nc] = f2bf(acc[mt][nt][reg] + bv);
                }
        } else {
            float bv = br[nc];
            #pragma unroll
            for (int mt = 0; mt < 4; ++mt)
                #pragma unroll
                for (int reg = 0; reg < 4; ++reg) {
                    int row = r0 + mt * 16 + q * 4 + reg;
                    if (row < nrows)
                        Yr[(size_t)row * CH + nc] = acc[mt][nt][reg] + bv;
                }
        }
    }
}

// ---------------------------------------------------------------------------
// Layer-2 GEMM (input pre-split as bf16 hi/lo planes): NO LDS, no barrier.
// ---------------------------------------------------------------------------
__global__ __launch_bounds__(256) void gemm_dual_mfma_pl(
        const unsigned short* __restrict__ Ah, const unsigned short* __restrict__ Al,
        const unsigned short* __restrict__ whTl, const unsigned short* __restrict__ wlTl,
        const unsigned short* __restrict__ whTr, const unsigned short* __restrict__ wlTr,
        const float* __restrict__ bl, const float* __restrict__ br,
        unsigned short* __restrict__ Ylb, float* __restrict__ Yr, int nrows) {
    int r0 = blockIdx.x * GR;
    int tid = (int)threadIdx.x;
    int wave = tid >> 6;
    int lane = tid & 63;
    int l15 = lane & 15, q = lane >> 4;

    size_t offA[4];
    #pragma unroll
    for (int mt = 0; mt < 4; ++mt) {
        int row = r0 + mt * 16 + l15;
        if (row > nrows - 1) row = nrows - 1;
        offA[mt] = (size_t)row * CH;
    }

    f32x4 acc[4][4];
    #pragma unroll
    for (int mt = 0; mt < 4; ++mt)
        #pragma unroll
        for (int nt = 0; nt < 4; ++nt) acc[mt][nt] = (f32x4)0.f;

    const unsigned short* bhp[4];
    const unsigned short* blp_[4];
    int ncol[4];
    #pragma unroll
    for (int nt = 0; nt < 4; ++nt) {
        int n = (wave * 4 + nt) * 16 + l15;
        ncol[nt] = n;
        int nn = n & 127;
        bhp[nt]  = ((n < CH) ? whTl : whTr) + (size_t)nn * CH;
        blp_[nt] = ((n < CH) ? wlTl : wlTr) + (size_t)nn * CH;
    }

    for (int kt = 0; kt < 4; ++kt) {
        int kofs = kt * 32 + q * 8;
        short8 ah[4], al[4];
        #pragma unroll
        for (int mt = 0; mt < 4; ++mt) {
            ah[mt] = *(const short8*)(Ah + offA[mt] + kofs);
            al[mt] = *(const short8*)(Al + offA[mt] + kofs);
        }
        #pragma unroll
        for (int nt = 0; nt < 4; ++nt) {
            short8 bh8 = *(const short8*)(bhp[nt] + kofs);
            short8 bl8 = *(const short8*)(blp_[nt] + kofs);
            #pragma unroll
            for (int mt = 0; mt < 4; ++mt) {
                acc[mt][nt] = __builtin_amdgcn_mfma_f32_16x16x32_bf16(
                                  ah[mt], bh8, acc[mt][nt], 0, 0, 0);
                acc[mt][nt] = __builtin_amdgcn_mfma_f32_16x16x32_bf16(
                                  al[mt], bh8, acc[mt][nt], 0, 0, 0);
                acc[mt][nt] = __builtin_amdgcn_mfma_f32_16x16x32_bf16(
                                  ah[mt], bl8, acc[mt][nt], 0, 0, 0);
            }
        }
    }

    #pragma unroll
    for (int nt = 0; nt < 4; ++nt) {
        int n = ncol[nt];
        int nc = n & 127;
        if (n < CH) {
            float bv = bl[nc];
            #pragma unroll
            for (int mt = 0; mt < 4; ++mt)
                #pragma unroll
                for (int reg = 0; reg < 4; ++reg) {
                    int row = r0 + mt * 16 + q * 4 + reg;
                    if (row < nrows)
                        Ylb[(size_t)row * CH + nc] = f2bf(acc[mt][nt][reg] + bv);
                }
        } else {
            float bv = br[nc];
            #pragma unroll
            for (int mt = 0; mt < 4; ++mt)
                #pragma unroll
                for (int reg = 0; reg < 4; ++reg) {
                    int row = r0 + mt * 16 + q * 4 + reg;
                    if (row < nrows)
                        Yr[(size_t)row * CH + nc] = acc[mt][nt][reg] + bv;
                }
        }
    }
}

// ---------------------------------------------------------------------------
// Fused GATv2 edge pass, v6: R7's 4-edge structure (one edge per quarter-wave,
// single prefetch) with float2-packed channel math (v_pk_fma_f32 et al on
// CDNA4). 16 lanes per edge row, 8 bf16 ch/lane as 4 x float2.
// SPLITOUT: write output as trunc-split bf16 hi/lo planes (layer-1 -> gemm2).
// ---------------------------------------------------------------------------
template <int HEADS, bool RELU, bool SPLITOUT>
__global__ __launch_bounds__(256) void node_pass(
        const unsigned short* __restrict__ xlb,   // [N][128] bf16 bits
        const float* __restrict__ xr,
        const float* __restrict__ att,    // 128 floats, flat (H, C/H)
        const float* __restrict__ bias,   // 128 floats
        const int* __restrict__ offs, const int* __restrict__ srcs,
        float* __restrict__ outf,
        unsigned short* __restrict__ outh, unsigned short* __restrict__ outl) {
    constexpr int GL = (CH / HEADS) / 8;     // lanes per head group: 4 or 16
    int wave = (int)threadIdx.x >> 6;
    int i = blockIdx.x * 4 + wave;
    int lane = (int)threadIdx.x & 63;
    int g = lane >> 4;                       // quarter 0..3
    int l16 = lane & 15;
    int c0 = l16 * 8;                        // this lane's 8 channels

    f32x2 r2[4], a2[4], s2[4];
    {
        const float4* xrp = (const float4*)(xr + (size_t)i * CH + c0);
        float4 r0 = xrp[0], r1 = xrp[1];
        r2[0] = (f32x2){r0.x, r0.y}; r2[1] = (f32x2){r0.z, r0.w};
        r2[2] = (f32x2){r1.x, r1.y}; r2[3] = (f32x2){r1.z, r1.w};
        const float4* atp = (const float4*)(att + c0);
        float4 a0 = atp[0], a1 = atp[1];
        a2[0] = (f32x2){a0.x, a0.y} * LOG2E; a2[1] = (f32x2){a0.z, a0.w} * LOG2E;
        a2[2] = (f32x2){a1.x, a1.y} * LOG2E; a2[3] = (f32x2){a1.z, a1.w} * LOG2E;
    }
    // self row (bf16)
    uint4 us = *(const uint4*)(xlb + (size_t)i * CH + c0);
    bf8cvt2(us, s2);

    f32x2 td = (f32x2)0.f;
    #pragma unroll
    for (int k = 0; k < 4; ++k) {
        f32x2 z = s2[k] + r2[k];
        f32x2 l = __builtin_elementwise_max(z, z * NEG_SLOPE);
        td += l * a2[k];
    }
    float ts = td.x + td.y;
    #pragma unroll
    for (int msk = 1; msk < GL; msk <<= 1) ts += __shfl_xor(ts, msk);

    float m = (g == 0) ? ts : NINF;
    float d = (g == 0) ? 1.f : 0.f;
    f32x2 acc2[4];
    #pragma unroll
    for (int k = 0; k < 4; ++k) acc2[k] = (g == 0) ? s2[k] : (f32x2)0.f;

    int beg = offs[i], end = offs[i + 1];
    int deg = end - beg;
    int iters = (deg + 3) >> 2;
    if (iters > 0) {
        int last = end - 1;
        int e = beg + g;
        int si = srcs[min(e, last)];
        uint4 u = *(const uint4*)(xlb + (size_t)si * CH + c0);

        for (int it = 0; it < iters; ++it, e += 4) {
            bool valid = e < end;
            // prefetch next edge for this quarter (clamped: own segment only)
            int sn = srcs[min(e + 4, last)];
            uint4 un = *(const uint4*)(xlb + (size_t)sn * CH + c0);

            f32x2 f2[4];
            bf8cvt2(u, f2);
            f32x2 td2 = (f32x2)0.f;
            #pragma unroll
            for (int k = 0; k < 4; ++k) {
                f32x2 z = f2[k] + r2[k];
                f32x2 l = __builtin_elementwise_max(z, z * NEG_SLOPE);
                td2 += l * a2[k];
            }
            float t = td2.x + td2.y;
            #pragma unroll
            for (int msk = 1; msk < GL; msk <<= 1) t += __shfl_xor(t, msk);
            t = valid ? t : NINF;

            float nm = fmaxf(m, t);
            float sc = exp2f(m - nm);
            float p  = valid ? exp2f(t - nm) : 0.f;
            d = d * sc + p;
            #pragma unroll
            for (int k = 0; k < 4; ++k) acc2[k] = acc2[k] * sc + f2[k] * p;
            m = nm;
            u = un;
        }
    }

    // merge the 4 quarter-wave states (butterfly: all lanes converge)
    #pragma unroll
    for (int msk = 16; msk <= 32; msk <<= 1) {
        float mo  = __shfl_xor(m, msk);
        float dof = __shfl_xor(d, msk);
        float nm = fmaxf(m, mo);
        float s0 = exp2f(m - nm), s1 = exp2f(mo - nm);
        d = d * s0 + dof * s1;
        #pragma unroll
        for (int k = 0; k < 4; ++k) {
            f32x2 ao;
            ao.x = __shfl_xor(acc2[k].x, msk);
            ao.y = __shfl_xor(acc2[k].y, msk);
            acc2[k] = acc2[k] * s0 + ao * s1;
        }
        m = nm;
    }

    if (g == 0) {
        float inv = 1.0f / d;
        const float4* bp = (const float4*)(bias + c0);
        float4 b0 = bp[0], b1 = bp[1];
        float bb[8] = {b0.x, b0.y, b0.z, b0.w, b1.x, b1.y, b1.z, b1.w};
        float o[8];
        #pragma unroll
        for (int k = 0; k < 4; ++k) {
            o[2*k]   = acc2[k].x * inv + bb[2*k];
            o[2*k+1] = acc2[k].y * inv + bb[2*k+1];
        }
        #pragma unroll
        for (int c = 0; c < 8; ++c)
            if (RELU) o[c] = fmaxf(o[c], 0.f);
        if (SPLITOUT) {
            unsigned hu[8];
            float lo[8];
            #pragma unroll
            for (int c = 0; c < 8; ++c) {
                hu[c] = fbits(o[c]) & 0xFFFF0000u;
                lo[c] = o[c] - asf(hu[c]);
            }
            uint4 ph, pl;
            ph.x = (hu[0] >> 16) | hu[1];  ph.y = (hu[2] >> 16) | hu[3];
            ph.z = (hu[4] >> 16) | hu[5];  ph.w = (hu[6] >> 16) | hu[7];
            pl.x = (fbits(lo[0]) >> 16) | (fbits(lo[1]) & 0xFFFF0000u);
            pl.y = (fbits(lo[2]) >> 16) | (fbits(lo[3]) & 0xFFFF0000u);
            pl.z = (fbits(lo[4]) >> 16) | (fbits(lo[5]) & 0xFFFF0000u);
            pl.w = (fbits(lo[6]) >> 16) | (fbits(lo[7]) & 0xFFFF0000u);
            *(uint4*)(outh + (size_t)i * CH + c0) = ph;
            *(uint4*)(outl + (size_t)i * CH + c0) = pl;
        } else {
            float4 w0 = make_float4(o[0], o[1], o[2], o[3]);
            float4 w1 = make_float4(o[4], o[5], o[6], o[7]);
            float4* op = (float4*)(outf + (size_t)i * CH + c0);
            op[0] = w0; op[1] = w1;
        }
    }
}

// ---------------------------------------------------------------------------
extern "C" void kernel_launch(void* const* d_in, const int* in_sizes, int n_in,
                              void* d_out, int out_size, void* d_ws, size_t ws_size,
                              hipStream_t stream) {
    const float* x     = (const float*)d_in[0];
    const void*  eidx  = d_in[1];
    const float* W1l   = (const float*)d_in[2];
    const float* b1l   = (const float*)d_in[3];
    const float* W1r   = (const float*)d_in[4];
    const float* b1r   = (const float*)d_in[5];
    const float* att1  = (const float*)d_in[6];
    const float* bias1 = (const float*)d_in[7];
    const float* W2l   = (const float*)d_in[8];
    const float* b2l   = (const float*)d_in[9];
    const float* W2r   = (const float*)d_in[10];
    const float* b2r   = (const float*)d_in[11];
    const float* att2  = (const float*)d_in[12];
    const float* bias2 = (const float*)d_in[13];
    float* out = (float*)d_out;

    // workspace layout
    unsigned short* xlb = (unsigned short*)d_ws;        // N*128 bf16 (attn side)
    float* xr = (float*)(xlb + (size_t)NODES * CH);     // N*128 fp32 (dst side)
    unsigned short* hbh = (unsigned short*)(xr + (size_t)NODES * CH); // N*128 u16
    unsigned short* hbl = hbh + (size_t)NODES * CH;     // N*128 u16
    int* offs   = (int*)(hbl + (size_t)NODES * CH);     // N+1
    int* cnt    = offs + (NODES + 1);                   // N
    int* cursor = cnt + NODES;                          // N
    int* srcs   = cursor + NODES;                       // E
    int* flag   = srcs + NEDGE;                         // 1
    int* bsum   = flag + 1;                             // NBLK
    unsigned short* wbuf =
        (unsigned short*)(((uintptr_t)(bsum + NBLK) + 15) & ~(uintptr_t)15);
    unsigned short* w1lh = wbuf;              unsigned short* w1ll = wbuf + 16384;
    unsigned short* w1rh = wbuf + 32768;      unsigned short* w1rl = wbuf + 49152;
    unsigned short* w2lh = wbuf + 65536;      unsigned short* w2ll = wbuf + 81920;
    unsigned short* w2rh = wbuf + 98304;      unsigned short* w2rl = wbuf + 114688;

    const int GG = (NODES + GR - 1) / GR;
    const int PG = NSLICE * 8;               // partitioned hist/scatter grid

    // prep (zero cnt + dtype detect + W split/transpose) and CSR build
    prep_kernel<<<ZB + 256, 256, 0, stream>>>(eidx, flag, cnt,
                                              W1l, W1r, W2l, W2r, wbuf);
    hist_part_kernel<<<PG, 256, 0, stream>>>(eidx, flag, cnt);
    scan1_kernel<<<NBLK, 256, 0, stream>>>(cnt, bsum);
    scan3_kernel<<<NBLK, 256, 0, stream>>>(cnt, bsum, offs, cursor);
    scatter_part_kernel<<<PG, 256, 0, stream>>>(eidx, flag, cursor, srcs);

    // layer 1
    gemm_dual_mfma<<<GG, 256, 0, stream>>>(x, w1lh, w1ll, w1rh, w1rl,
                                           b1l, b1r, xlb, xr, NODES);
    node_pass<4, true, true><<<(NODES + 3) / 4, 256, 0, stream>>>(
        xlb, xr, att1, bias1, offs, srcs, nullptr, hbh, hbl);

    // layer 2
    gemm_dual_mfma_pl<<<GG, 256, 0, stream>>>(hbh, hbl, w2lh, w2ll, w2rh, w2rl,
                                              b2l, b2r, xlb, xr, NODES);
    node_pass<1, false, false><<<(NODES + 3) / 4, 256, 0, stream>>>(
        xlb, xr, att2, bias2, offs, srcs, out, nullptr, nullptr);
}

// Round 10
// 355.075 us; speedup vs baseline: 1.0597x; 1.0258x over previous
//
#include <hip/hip_runtime.h>
#include <hip/hip_bf16.h>

#define NODES 50000
#define NEDGE 800000
#define CH 128          // all of IN/HID/OUT
#define NEG_SLOPE 0.2f
#define SCAN_CHUNK 2048
#define NBLK ((NODES + SCAN_CHUNK - 1) / SCAN_CHUNK)   // 25
#define NINF -1.0e30f
#define LOG2E 1.44269504088896340736f
#define NSLICE 400
#define SSLICE (NEDGE / NSLICE)       // 2000 edges per slice
#define ZB ((NODES + 255) / 256)      // 196 zero-blocks

typedef short short8 __attribute__((ext_vector_type(8)));
typedef float f32x4 __attribute__((ext_vector_type(4)));
typedef float f32x2 __attribute__((ext_vector_type(2)));

__device__ __forceinline__ unsigned fbits(float f) {
    union { float f; unsigned u; } v; v.f = f; return v.u;
}
__device__ __forceinline__ float asf(unsigned u) {
    union { float f; unsigned u; } v; v.u = u; return v.f;
}
// fp32 -> bf16 (RNE)
__device__ __forceinline__ unsigned short f2bf(float f) {
    unsigned u = fbits(f);
    unsigned r = u + 0x7fff + ((u >> 16) & 1);
    return (unsigned short)(r >> 16);
}
__device__ __forceinline__ float bf2f(unsigned short h) {
    return asf(((unsigned)h) << 16);
}
// 8 bf16 (as uint4) -> 4 x float2 (packed-math friendly)
__device__ __forceinline__ void bf8cvt2(uint4 u, f32x2* f) {
    f[0] = (f32x2){asf(u.x << 16), asf(u.x & 0xFFFF0000u)};
    f[1] = (f32x2){asf(u.y << 16), asf(u.y & 0xFFFF0000u)};
    f[2] = (f32x2){asf(u.z << 16), asf(u.z & 0xFFFF0000u)};
    f[3] = (f32x2){asf(u.w << 16), asf(u.w & 0xFFFF0000u)};
}
// dst-range set for XCD-partitioned CSR build
__device__ __forceinline__ int dset(int dst) {
    return (int)(((unsigned)dst * 8u) / 50000u);   // exact partition of [0,50000)
}

// ---------------------------------------------------------------------------
// prep: zero histogram + detect edge dtype + W->bf16 hi/lo transpose, fused.
// ---------------------------------------------------------------------------
__global__ __launch_bounds__(256) void prep_kernel(const void* idx, int* flag,
                                                   int* cnt,
                                                   const float* __restrict__ W0,
                                                   const float* __restrict__ W1,
                                                   const float* __restrict__ W2,
                                                   const float* __restrict__ W3,
                                                   unsigned short* __restrict__ wbase) {
    int b = (int)blockIdx.x;
    if (b < ZB) {
        int t = b * 256 + (int)threadIdx.x;
        if (t < NODES) cnt[t] = 0;
        if (b == 0 && threadIdx.x < 64) {
            const int* w = (const int*)idx;
            int nz = (w[2 * threadIdx.x + 1] != 0) ? 1 : 0;
            unsigned long long bal = __ballot(nz);
            if (threadIdx.x == 0) *flag = (bal == 0ull) ? 1 : 0;
        }
        return;
    }
    int wb = b - ZB;                               // 0..255
    int which = wb >> 6;
    const float* W = (which == 0) ? W0 : (which == 1) ? W1 : (which == 2) ? W2 : W3;
    unsigned short* hiT = wbase + (size_t)which * 32768;
    unsigned short* loT = hiT + 16384;
    int i = (wb & 63) * 256 + (int)threadIdx.x;    // 0..16383
    int k = i >> 7, n = i & 127;
    float f = W[i];
    unsigned short h = f2bf(f);
    unsigned short l = f2bf(f - bf2f(h));
    hiT[n * CH + k] = h;
    loT[n * CH + k] = l;
}

// ---------------------------------------------------------------------------
// XCD-partitioned histogram
// ---------------------------------------------------------------------------
__global__ __launch_bounds__(256) void hist_part_kernel(const void* idx,
                                                        const int* flag,
                                                        int* cnt) {
    int set = blockIdx.x & 7;
    int slice = blockIdx.x >> 3;
    int base = slice * SSLICE;
    int endE = base + SSLICE;
    int i64 = *flag;
    const int* w = (const int*)idx;
    for (int e = base + (int)threadIdx.x; e < endE; e += 256) {
        int dst = i64 ? w[2 * (NEDGE + e)] : w[NEDGE + e];
        if (dset(dst) == set) atomicAdd(&cnt[dst], 1);
    }
}

__global__ __launch_bounds__(256) void scan1_kernel(const int* __restrict__ cnt,
                                                    int* __restrict__ bsum) {
    int base = blockIdx.x * SCAN_CHUNK + (int)threadIdx.x * 8;
    int s = 0;
    #pragma unroll
    for (int k = 0; k < 8; ++k) {
        int i = base + k;
        s += (i < NODES) ? cnt[i] : 0;
    }
    #pragma unroll
    for (int m = 1; m < 64; m <<= 1) s += __shfl_xor(s, m);
    __shared__ int ws[4];
    if ((threadIdx.x & 63) == 0) ws[threadIdx.x >> 6] = s;
    __syncthreads();
    if (threadIdx.x == 0) bsum[blockIdx.x] = ws[0] + ws[1] + ws[2] + ws[3];
}

__global__ __launch_bounds__(256) void scan3_kernel(const int* __restrict__ cnt,
                                                    const int* __restrict__ bsum,
                                                    int* __restrict__ offs,
                                                    int* __restrict__ cursor) {
    int tid = (int)threadIdx.x;
    int bpre = 0;
    #pragma unroll
    for (int b = 0; b < NBLK; ++b) bpre += (b < (int)blockIdx.x) ? bsum[b] : 0;

    int base = blockIdx.x * SCAN_CHUNK + tid * 8;
    int v[8];
    int s = 0;
    #pragma unroll
    for (int k = 0; k < 8; ++k) {
        int i = base + k;
        v[k] = (i < NODES) ? cnt[i] : 0;
        s += v[k];
    }
    int lane = tid & 63;
    int incl = s;
    #pragma unroll
    for (int m = 1; m < 64; m <<= 1) {
        int t = __shfl_up(incl, m);
        if (lane >= m) incl += t;
    }
    __shared__ int wtot[4];
    if (lane == 63) wtot[tid >> 6] = incl;
    __syncthreads();
    int w = tid >> 6;
    int wbase = 0;
    #pragma unroll
    for (int k = 0; k < 4; ++k) wbase += (k < w) ? wtot[k] : 0;
    int excl = bpre + wbase + (incl - s);
    #pragma unroll
    for (int k = 0; k < 8; ++k) {
        int i = base + k;
        if (i < NODES) { offs[i] = excl; cursor[i] = excl; }
        excl += v[k];
    }
    if (blockIdx.x == 0 && tid == 0) offs[NODES] = NEDGE;
}

// ---------------------------------------------------------------------------
// XCD-partitioned scatter
// ---------------------------------------------------------------------------
__global__ __launch_bounds__(256) void scatter_part_kernel(const void* idx,
                                                           const int* flag,
                                                           int* cursor,
                                                           int* __restrict__ srcs) {
    int set = blockIdx.x & 7;
    int slice = blockIdx.x >> 3;
    int base = slice * SSLICE;
    int endE = base + SSLICE;
    int i64 = *flag;
    const int* w = (const int*)idx;
    for (int e = base + (int)threadIdx.x; e < endE; e += 256) {
        int dst = i64 ? w[2 * (NEDGE + e)] : w[NEDGE + e];
        if (dset(dst) == set) {
            int src = i64 ? w[2 * e] : w[e];
            int pos = atomicAdd(&cursor[dst], 1);
            srcs[pos] = src;
        }
    }
}

// ---------------------------------------------------------------------------
// Layer-1 GEMM (fp32 input, LDS-staged split-bf16 MFMA), 512 threads:
// 8 waves/block, each wave owns 2 N-tiles (32 cols) of the 256-wide output.
// Ylb = bf16(X@Wl + bl), Yr = X@Wr + br (fp32).
// ---------------------------------------------------------------------------
#define GR 64
#define LDP 136   // padded row stride in shorts (272 B)

__global__ __launch_bounds__(512) void gemm_dual_mfma(
        const float* __restrict__ X,
        const unsigned short* __restrict__ whTl, const unsigned short* __restrict__ wlTl,
        const unsigned short* __restrict__ whTr, const unsigned short* __restrict__ wlTr,
        const float* __restrict__ bl, const float* __restrict__ br,
        unsigned short* __restrict__ Ylb, float* __restrict__ Yr, int nrows) {
    __shared__ unsigned short xh[GR][LDP];
    __shared__ unsigned short xlo[GR][LDP];

    int r0 = blockIdx.x * GR;
    int tid = (int)threadIdx.x;

    // ---- stage X tile: fp32 -> hi/lo bf16 (truncation split), packed ----
    {
        int row = tid >> 3;              // 0..63
        int c0 = (tid & 7) * 16;         // col start, 16 cols per thread
        const float* src = X + (size_t)(r0 + row) * CH + c0;
        bool valid = (r0 + row) < nrows;
        #pragma unroll
        for (int j = 0; j < 16; j += 4) {
            float4 v = valid ? *(const float4*)(src + j)
                             : make_float4(0.f, 0.f, 0.f, 0.f);
            unsigned ux = fbits(v.x), uy = fbits(v.y);
            unsigned uz = fbits(v.z), uw = fbits(v.w);
            unsigned hx = ux & 0xFFFF0000u, hy = uy & 0xFFFF0000u;
            unsigned hz = uz & 0xFFFF0000u, hw = uw & 0xFFFF0000u;
            uint2 hp;
            hp.x = (ux >> 16) | hy;
            hp.y = (uz >> 16) | hw;
            float lx = v.x - asf(hx), ly = v.y - asf(hy);
            float lz = v.z - asf(hz), lw = v.w - asf(hw);
            uint2 lp;
            lp.x = (fbits(lx) >> 16) | (fbits(ly) & 0xFFFF0000u);
            lp.y = (fbits(lz) >> 16) | (fbits(lw) & 0xFFFF0000u);
            *(uint2*)&xh[row][c0 + j]  = hp;
            *(uint2*)&xlo[row][c0 + j] = lp;
        }
    }
    __syncthreads();

    int wave = tid >> 6;      // 0..7: n-eighth (32 cols each)
    int lane = tid & 63;
    int l15 = lane & 15, q = lane >> 4;

    f32x4 acc[4][2];
    #pragma unroll
    for (int mt = 0; mt < 4; ++mt)
        #pragma unroll
        for (int nt = 0; nt < 2; ++nt) acc[mt][nt] = (f32x4)0.f;

    const unsigned short* bhp[2];
    const unsigned short* blp_[2];
    int ncol[2];
    #pragma unroll
    for (int nt = 0; nt < 2; ++nt) {
        int n = (wave * 2 + nt) * 16 + l15;       // 0..255
        ncol[nt] = n;
        int nn = n & 127;
        bhp[nt]  = ((n < CH) ? whTl : whTr) + (size_t)nn * CH;
        blp_[nt] = ((n < CH) ? wlTl : wlTr) + (size_t)nn * CH;
    }

    for (int kt = 0; kt < 4; ++kt) {
        int kofs = kt * 32 + q * 8;
        short8 ah[4], al[4];
        #pragma unroll
        for (int mt = 0; mt < 4; ++mt) {
            ah[mt] = *(const short8*)&xh[mt * 16 + l15][kofs];
            al[mt] = *(const short8*)&xlo[mt * 16 + l15][kofs];
        }
        #pragma unroll
        for (int nt = 0; nt < 2; ++nt) {
            short8 bh8 = *(const short8*)(bhp[nt] + kofs);
            short8 bl8 = *(const short8*)(blp_[nt] + kofs);
            #pragma unroll
            for (int mt = 0; mt < 4; ++mt) {
                acc[mt][nt] = __builtin_amdgcn_mfma_f32_16x16x32_bf16(
                                  ah[mt], bh8, acc[mt][nt], 0, 0, 0);
                acc[mt][nt] = __builtin_amdgcn_mfma_f32_16x16x32_bf16(
                                  al[mt], bh8, acc[mt][nt], 0, 0, 0);
                acc[mt][nt] = __builtin_amdgcn_mfma_f32_16x16x32_bf16(
                                  ah[mt], bl8, acc[mt][nt], 0, 0, 0);
            }
        }
    }

    // ---- epilogue: C/D layout col=lane&15, row=q*4+reg ----
    #pragma unroll
    for (int nt = 0; nt < 2; ++nt) {
        int n = ncol[nt];
        int nc = n & 127;
        if (n < CH) {
            float bv = bl[nc];
            #pragma unroll
            for (int mt = 0; mt < 4; ++mt)
                #pragma unroll
                for (int reg = 0; reg < 4; ++reg) {
                    int row = r0 + mt * 16 + q * 4 + reg;
                    if (row < nrows)
                        Ylb[(size_t)row * CH + nc] = f2bf(acc[mt][nt][reg] + bv);
                }
        } else {
            float bv = br[nc];
            #pragma unroll
            for (int mt = 0; mt < 4; ++mt)
                #pragma unroll
                for (int reg = 0; reg < 4; ++reg) {
                    int row = r0 + mt * 16 + q * 4 + reg;
                    if (row < nrows)
                        Yr[(size_t)row * CH + nc] = acc[mt][nt][reg] + bv;
                }
        }
    }
}

// ---------------------------------------------------------------------------
// Layer-2 GEMM (input pre-split as bf16 hi/lo planes): NO LDS, 512 threads,
// 8 waves/block, each wave 2 N-tiles. A-fragments direct from global.
// ---------------------------------------------------------------------------
__global__ __launch_bounds__(512) void gemm_dual_mfma_pl(
        const unsigned short* __restrict__ Ah, const unsigned short* __restrict__ Al,
        const unsigned short* __restrict__ whTl, const unsigned short* __restrict__ wlTl,
        const unsigned short* __restrict__ whTr, const unsigned short* __restrict__ wlTr,
        const float* __restrict__ bl, const float* __restrict__ br,
        unsigned short* __restrict__ Ylb, float* __restrict__ Yr, int nrows) {
    int r0 = blockIdx.x * GR;
    int tid = (int)threadIdx.x;
    int wave = tid >> 6;      // 0..7
    int lane = tid & 63;
    int l15 = lane & 15, q = lane >> 4;

    size_t offA[4];
    #pragma unroll
    for (int mt = 0; mt < 4; ++mt) {
        int row = r0 + mt * 16 + l15;
        if (row > nrows - 1) row = nrows - 1;
        offA[mt] = (size_t)row * CH;
    }

    f32x4 acc[4][2];
    #pragma unroll
    for (int mt = 0; mt < 4; ++mt)
        #pragma unroll
        for (int nt = 0; nt < 2; ++nt) acc[mt][nt] = (f32x4)0.f;

    const unsigned short* bhp[2];
    const unsigned short* blp_[2];
    int ncol[2];
    #pragma unroll
    for (int nt = 0; nt < 2; ++nt) {
        int n = (wave * 2 + nt) * 16 + l15;
        ncol[nt] = n;
        int nn = n & 127;
        bhp[nt]  = ((n < CH) ? whTl : whTr) + (size_t)nn * CH;
        blp_[nt] = ((n < CH) ? wlTl : wlTr) + (size_t)nn * CH;
    }

    for (int kt = 0; kt < 4; ++kt) {
        int kofs = kt * 32 + q * 8;
        short8 ah[4], al[4];
        #pragma unroll
        for (int mt = 0; mt < 4; ++mt) {
            ah[mt] = *(const short8*)(Ah + offA[mt] + kofs);
            al[mt] = *(const short8*)(Al + offA[mt] + kofs);
        }
        #pragma unroll
        for (int nt = 0; nt < 2; ++nt) {
            short8 bh8 = *(const short8*)(bhp[nt] + kofs);
            short8 bl8 = *(const short8*)(blp_[nt] + kofs);
            #pragma unroll
            for (int mt = 0; mt < 4; ++mt) {
                acc[mt][nt] = __builtin_amdgcn_mfma_f32_16x16x32_bf16(
                                  ah[mt], bh8, acc[mt][nt], 0, 0, 0);
                acc[mt][nt] = __builtin_amdgcn_mfma_f32_16x16x32_bf16(
                                  al[mt], bh8, acc[mt][nt], 0, 0, 0);
                acc[mt][nt] = __builtin_amdgcn_mfma_f32_16x16x32_bf16(
                                  ah[mt], bl8, acc[mt][nt], 0, 0, 0);
            }
        }
    }

    #pragma unroll
    for (int nt = 0; nt < 2; ++nt) {
        int n = ncol[nt];
        int nc = n & 127;
        if (n < CH) {
            float bv = bl[nc];
            #pragma unroll
            for (int mt = 0; mt < 4; ++mt)
                #pragma unroll
                for (int reg = 0; reg < 4; ++reg) {
                    int row = r0 + mt * 16 + q * 4 + reg;
                    if (row < nrows)
                        Ylb[(size_t)row * CH + nc] = f2bf(acc[mt][nt][reg] + bv);
                }
        } else {
            float bv = br[nc];
            #pragma unroll
            for (int mt = 0; mt < 4; ++mt)
                #pragma unroll
                for (int reg = 0; reg < 4; ++reg) {
                    int row = r0 + mt * 16 + q * 4 + reg;
                    if (row < nrows)
                        Yr[(size_t)row * CH + nc] = acc[mt][nt][reg] + bv;
                }
        }
    }
}

// ---------------------------------------------------------------------------
// Fused GATv2 edge pass (R9 form): one node per wave, 16 lanes per edge row,
// float2-packed channel math, one prefetched edge per quarter-wave.
// SPLITOUT: write output as trunc-split bf16 hi/lo planes (layer-1 -> gemm2).
// ---------------------------------------------------------------------------
template <int HEADS, bool RELU, bool SPLITOUT>
__global__ __launch_bounds__(256) void node_pass(
        const unsigned short* __restrict__ xlb,   // [N][128] bf16 bits
        const float* __restrict__ xr,
        const float* __restrict__ att,    // 128 floats, flat (H, C/H)
        const float* __restrict__ bias,   // 128 floats
        const int* __restrict__ offs, const int* __restrict__ srcs,
        float* __restrict__ outf,
        unsigned short* __restrict__ outh, unsigned short* __restrict__ outl) {
    constexpr int GL = (CH / HEADS) / 8;     // lanes per head group: 4 or 16
    int wave = (int)threadIdx.x >> 6;
    int i = blockIdx.x * 4 + wave;
    int lane = (int)threadIdx.x & 63;
    int g = lane >> 4;                       // quarter 0..3
    int l16 = lane & 15;
    int c0 = l16 * 8;                        // this lane's 8 channels

    f32x2 r2[4], a2[4], s2[4];
    {
        const float4* xrp = (const float4*)(xr + (size_t)i * CH + c0);
        float4 r0 = xrp[0], r1 = xrp[1];
        r2[0] = (f32x2){r0.x, r0.y}; r2[1] = (f32x2){r0.z, r0.w};
        r2[2] = (f32x2){r1.x, r1.y}; r2[3] = (f32x2){r1.z, r1.w};
        const float4* atp = (const float4*)(att + c0);
        float4 a0 = atp[0], a1 = atp[1];
        a2[0] = (f32x2){a0.x, a0.y} * LOG2E; a2[1] = (f32x2){a0.z, a0.w} * LOG2E;
        a2[2] = (f32x2){a1.x, a1.y} * LOG2E; a2[3] = (f32x2){a1.z, a1.w} * LOG2E;
    }
    // self row (bf16)
    uint4 us = *(const uint4*)(xlb + (size_t)i * CH + c0);
    bf8cvt2(us, s2);

    f32x2 td = (f32x2)0.f;
    #pragma unroll
    for (int k = 0; k < 4; ++k) {
        f32x2 z = s2[k] + r2[k];
        f32x2 l = __builtin_elementwise_max(z, z * NEG_SLOPE);
        td += l * a2[k];
    }
    float ts = td.x + td.y;
    #pragma unroll
    for (int msk = 1; msk < GL; msk <<= 1) ts += __shfl_xor(ts, msk);

    float m = (g == 0) ? ts : NINF;
    float d = (g == 0) ? 1.f : 0.f;
    f32x2 acc2[4];
    #pragma unroll
    for (int k = 0; k < 4; ++k) acc2[k] = (g == 0) ? s2[k] : (f32x2)0.f;

    int beg = offs[i], end = offs[i + 1];
    int deg = end - beg;
    int iters = (deg + 3) >> 2;
    if (iters > 0) {
        int last = end - 1;
        int e = beg + g;
        int si = srcs[min(e, last)];
        uint4 u = *(const uint4*)(xlb + (size_t)si * CH + c0);

        for (int it = 0; it < iters; ++it, e += 4) {
            bool valid = e < end;
            // prefetch next edge for this quarter (clamped: own segment only)
            int sn = srcs[min(e + 4, last)];
            uint4 un = *(const uint4*)(xlb + (size_t)sn * CH + c0);

            f32x2 f2[4];
            bf8cvt2(u, f2);
            f32x2 td2 = (f32x2)0.f;
            #pragma unroll
            for (int k = 0; k < 4; ++k) {
                f32x2 z = f2[k] + r2[k];
                f32x2 l = __builtin_elementwise_max(z, z * NEG_SLOPE);
                td2 += l * a2[k];
            }
            float t = td2.x + td2.y;
            #pragma unroll
            for (int msk = 1; msk < GL; msk <<= 1) t += __shfl_xor(t, msk);
            t = valid ? t : NINF;

            float nm = fmaxf(m, t);
            float sc = exp2f(m - nm);
            float p  = valid ? exp2f(t - nm) : 0.f;
            d = d * sc + p;
            #pragma unroll
            for (int k = 0; k < 4; ++k) acc2[k] = acc2[k] * sc + f2[k] * p;
            m = nm;
            u = un;
        }
    }

    // merge the 4 quarter-wave states (butterfly: all lanes converge)
    #pragma unroll
    for (int msk = 16; msk <= 32; msk <<= 1) {
        float mo  = __shfl_xor(m, msk);
        float dof = __shfl_xor(d, msk);
        float nm = fmaxf(m, mo);
        float s0 = exp2f(m - nm), s1 = exp2f(mo - nm);
        d = d * s0 + dof * s1;
        #pragma unroll
        for (int k = 0; k < 4; ++k) {
            f32x2 ao;
            ao.x = __shfl_xor(acc2[k].x, msk);
            ao.y = __shfl_xor(acc2[k].y, msk);
            acc2[k] = acc2[k] * s0 + ao * s1;
        }
        m = nm;
    }

    if (g == 0) {
        float inv = 1.0f / d;
        const float4* bp = (const float4*)(bias + c0);
        float4 b0 = bp[0], b1 = bp[1];
        float bb[8] = {b0.x, b0.y, b0.z, b0.w, b1.x, b1.y, b1.z, b1.w};
        float o[8];
        #pragma unroll
        for (int k = 0; k < 4; ++k) {
            o[2*k]   = acc2[k].x * inv + bb[2*k];
            o[2*k+1] = acc2[k].y * inv + bb[2*k+1];
        }
        #pragma unroll
        for (int c = 0; c < 8; ++c)
            if (RELU) o[c] = fmaxf(o[c], 0.f);
        if (SPLITOUT) {
            unsigned hu[8];
            float lo[8];
            #pragma unroll
            for (int c = 0; c < 8; ++c) {
                hu[c] = fbits(o[c]) & 0xFFFF0000u;
                lo[c] = o[c] - asf(hu[c]);
            }
            uint4 ph, pl;
            ph.x = (hu[0] >> 16) | hu[1];  ph.y = (hu[2] >> 16) | hu[3];
            ph.z = (hu[4] >> 16) | hu[5];  ph.w = (hu[6] >> 16) | hu[7];
            pl.x = (fbits(lo[0]) >> 16) | (fbits(lo[1]) & 0xFFFF0000u);
            pl.y = (fbits(lo[2]) >> 16) | (fbits(lo[3]) & 0xFFFF0000u);
            pl.z = (fbits(lo[4]) >> 16) | (fbits(lo[5]) & 0xFFFF0000u);
            pl.w = (fbits(lo[6]) >> 16) | (fbits(lo[7]) & 0xFFFF0000u);
            *(uint4*)(outh + (size_t)i * CH + c0) = ph;
            *(uint4*)(outl + (size_t)i * CH + c0) = pl;
        } else {
            float4 w0 = make_float4(o[0], o[1], o[2], o[3]);
            float4 w1 = make_float4(o[4], o[5], o[6], o[7]);
            float4* op = (float4*)(outf + (size_t)i * CH + c0);
            op[0] = w0; op[1] = w1;
        }
    }
}

// ---------------------------------------------------------------------------
extern "C" void kernel_launch(void* const* d_in, const int* in_sizes, int n_in,
                              void* d_out, int out_size, void* d_ws, size_t ws_size,
                              hipStream_t stream) {
    const float* x     = (const float*)d_in[0];
    const void*  eidx  = d_in[1];
    const float* W1l   = (const float*)d_in[2];
    const float* b1l   = (const float*)d_in[3];
    const float* W1r   = (const float*)d_in[4];
    const float* b1r   = (const float*)d_in[5];
    const float* att1  = (const float*)d_in[6];
    const float* bias1 = (const float*)d_in[7];
    const float* W2l   = (const float*)d_in[8];
    const float* b2l   = (const float*)d_in[9];
    const float* W2r   = (const float*)d_in[10];
    const float* b2r   = (const float*)d_in[11];
    const float* att2  = (const float*)d_in[12];
    const float* bias2 = (const float*)d_in[13];
    float* out = (float*)d_out;

    // workspace layout
    unsigned short* xlb = (unsigned short*)d_ws;        // N*128 bf16 (attn side)
    float* xr = (float*)(xlb + (size_t)NODES * CH);     // N*128 fp32 (dst side)
    unsigned short* hbh = (unsigned short*)(xr + (size_t)NODES * CH); // N*128 u16
    unsigned short* hbl = hbh + (size_t)NODES * CH;     // N*128 u16
    int* offs   = (int*)(hbl + (size_t)NODES * CH);     // N+1
    int* cnt    = offs + (NODES + 1);                   // N
    int* cursor = cnt + NODES;                          // N
    int* srcs   = cursor + NODES;                       // E
    int* flag   = srcs + NEDGE;                         // 1
    int* bsum   = flag + 1;                             // NBLK
    unsigned short* wbuf =
        (unsigned short*)(((uintptr_t)(bsum + NBLK) + 15) & ~(uintptr_t)15);
    unsigned short* w1lh = wbuf;              unsigned short* w1ll = wbuf + 16384;
    unsigned short* w1rh = wbuf + 32768;      unsigned short* w1rl = wbuf + 49152;
    unsigned short* w2lh = wbuf + 65536;      unsigned short* w2ll = wbuf + 81920;
    unsigned short* w2rh = wbuf + 98304;      unsigned short* w2rl = wbuf + 114688;

    const int GG = (NODES + GR - 1) / GR;
    const int PG = NSLICE * 8;               // partitioned hist/scatter grid

    // prep (zero cnt + dtype detect + W split/transpose) and CSR build
    prep_kernel<<<ZB + 256, 256, 0, stream>>>(eidx, flag, cnt,
                                              W1l, W1r, W2l, W2r, wbuf);
    hist_part_kernel<<<PG, 256, 0, stream>>>(eidx, flag, cnt);
    scan1_kernel<<<NBLK, 256, 0, stream>>>(cnt, bsum);
    scan3_kernel<<<NBLK, 256, 0, stream>>>(cnt, bsum, offs, cursor);
    scatter_part_kernel<<<PG, 256, 0, stream>>>(eidx, flag, cursor, srcs);

    // layer 1
    gemm_dual_mfma<<<GG, 512, 0, stream>>>(x, w1lh, w1ll, w1rh, w1rl,
                                           b1l, b1r, xlb, xr, NODES);
    node_pass<4, true, true><<<(NODES + 3) / 4, 256, 0, stream>>>(
        xlb, xr, att1, bias1, offs, srcs, nullptr, hbh, hbl);

    // layer 2
    gemm_dual_mfma_pl<<<GG, 512, 0, stream>>>(hbh, hbl, w2lh, w2ll, w2rh, w2rl,
                                              b2l, b2r, xlb, xr, NODES);
    node_pass<1, false, false><<<(NODES + 3) / 4, 256, 0, stream>>>(
        xlb, xr, att2, bias2, offs, srcs, out, nullptr, nullptr);
}